// Round 14
// baseline (507.399 us; speedup 1.0000x reference)
//
#include <hip/hip_runtime.h>

#define BATCH 256
#define D 128
#define TT 64
#define NPG 60
#define NCC 30
#define NQQ 15
#define EPG 135
#define NPROP 5
#define SKI 10

typedef __attribute__((ext_vector_type(8))) short bf16x8;
typedef __attribute__((ext_vector_type(4))) float f32x4;

union U8 { bf16x8 v; uint4 u; };

__device__ __forceinline__ unsigned short f2bf(float f) {
    union { float f; unsigned int i; } t;
    t.f = f;
    unsigned int r = t.i + 0x7fffu + ((t.i >> 16) & 1u);
    return (unsigned short)(r >> 16);
}
// packed truncation split: value = hi + lo, stored (hi<<16)|lo
__device__ __forceinline__ unsigned int pkv(float v) {
    unsigned int ih = __float_as_uint(v) & 0xffff0000u;
    float r = v - __uint_as_float(ih);
    return ih | (__float_as_uint(r) >> 16);
}
__device__ __forceinline__ float upkv(unsigned int p) {
    return __uint_as_float(p & 0xffff0000u) + __uint_as_float(p << 16);
}
// 8 packed elems -> hi/lo bf16x8 fragments (pure bit-ops, registers only)
__device__ __forceinline__ void unpack8(const unsigned int* s, bf16x8& hi, bf16x8& lo) {
    uint4 a = *(const uint4*)s;
    uint4 b = *(const uint4*)(s + 4);
    U8 h, l;
    h.u = make_uint4((a.x >> 16) | (a.y & 0xffff0000u), (a.z >> 16) | (a.w & 0xffff0000u),
                     (b.x >> 16) | (b.y & 0xffff0000u), (b.z >> 16) | (b.w & 0xffff0000u));
    l.u = make_uint4((a.x & 0xffffu) | (a.y << 16), (a.z & 0xffffu) | (a.w << 16),
                     (b.x & 0xffffu) | (b.y << 16), (b.z & 0xffffu) | (b.w << 16));
    hi = h.v; lo = l.v;
}
// truncation split of 8 fp32 (scalar, no scratch)
__device__ __forceinline__ void splitv(float4 a, float4 b, bf16x8& hi, bf16x8& lo) {
    unsigned int ia0=__float_as_uint(a.x), ia1=__float_as_uint(a.y);
    unsigned int ia2=__float_as_uint(a.z), ia3=__float_as_uint(a.w);
    unsigned int ib0=__float_as_uint(b.x), ib1=__float_as_uint(b.y);
    unsigned int ib2=__float_as_uint(b.z), ib3=__float_as_uint(b.w);
    U8 uh, ul;
    uh.u = make_uint4((ia0>>16)|(ia1&0xffff0000u), (ia2>>16)|(ia3&0xffff0000u),
                      (ib0>>16)|(ib1&0xffff0000u), (ib2>>16)|(ib3&0xffff0000u));
    float r0 = a.x - __uint_as_float(ia0&0xffff0000u);
    float r1 = a.y - __uint_as_float(ia1&0xffff0000u);
    float r2 = a.z - __uint_as_float(ia2&0xffff0000u);
    float r3 = a.w - __uint_as_float(ia3&0xffff0000u);
    float r4 = b.x - __uint_as_float(ib0&0xffff0000u);
    float r5 = b.y - __uint_as_float(ib1&0xffff0000u);
    float r6 = b.z - __uint_as_float(ib2&0xffff0000u);
    float r7 = b.w - __uint_as_float(ib3&0xffff0000u);
    ul.u = make_uint4((__float_as_uint(r0)>>16)|(__float_as_uint(r1)&0xffff0000u),
                      (__float_as_uint(r2)>>16)|(__float_as_uint(r3)&0xffff0000u),
                      (__float_as_uint(r4)>>16)|(__float_as_uint(r5)&0xffff0000u),
                      (__float_as_uint(r6)>>16)|(__float_as_uint(r7)&0xffff0000u));
    hi = uh.v; lo = ul.v;
}
__device__ __forceinline__ void split_bf(float v, unsigned short& hi, unsigned short& lo) {
    hi = f2bf(v);
    union { float f; unsigned int i; } t; t.i = ((unsigned int)hi) << 16;
    lo = f2bf(v - t.f);
}

#define MFMA3(ah, al, bh, bl, acc)                                              \
    acc = __builtin_amdgcn_mfma_f32_16x16x32_bf16(ah, bh, acc, 0, 0, 0);        \
    acc = __builtin_amdgcn_mfma_f32_16x16x32_bf16(al, bh, acc, 0, 0, 0);        \
    acc = __builtin_amdgcn_mfma_f32_16x16x32_bf16(ah, bl, acc, 0, 0, 0);

// ---------------- edge-constant precompute: uv (512 fp32) ----------------
__global__ void k_prep_uv(const float* __restrict__ ew, const float* __restrict__ eb,
                          const float* __restrict__ w1, const float* __restrict__ b1,
                          float* __restrict__ uv) {
    int t = threadIdx.x;  // 0..255
    float u = 0.f, v = 0.f;
    for (int d = 0; d < D; ++d) {
        float wv = w1[(256 + d) * 256 + t];
        u += ew[d] * wv;
        v += eb[d] * wv;
    }
    uv[t] = u;
    uv[256 + t] = v + b1[t];
}

// ------------- weight prep: frag-major hi/lo bf16 planes (RNE split) -------------
// elem o = ((nfr*KS + ks)*64 + lane)*8 + t -> n = nfr*16+(l&15), k = ks*32+(l>>4)*8+t
__global__ void k_prep_w2(const float* __restrict__ mw1, const float* __restrict__ mw2,
                          const float* __restrict__ uw1, const float* __restrict__ uw2,
                          const float* __restrict__ f1w, const float* __restrict__ f2w,
                          unsigned short* __restrict__ w1h, unsigned short* __restrict__ w1l,
                          unsigned short* __restrict__ w2h, unsigned short* __restrict__ w2l,
                          unsigned short* __restrict__ u1h, unsigned short* __restrict__ u1l,
                          unsigned short* __restrict__ u2h, unsigned short* __restrict__ u2l,
                          unsigned short* __restrict__ g1h, unsigned short* __restrict__ g1l,
                          unsigned short* __restrict__ g2h, unsigned short* __restrict__ g2l) {
    int idx = blockIdx.x * 512 + threadIdx.x;
    int o, KS;
    unsigned short *ph, *pl;
    int mtype;
    if (idx < 65536)        { o = idx;          KS = 8; ph = w1h; pl = w1l; mtype = 0; }  // W1cat [256n][256k]
    else if (idx < 98304)   { o = idx - 65536;  KS = 8; ph = w2h; pl = w2l; mtype = 1; }  // W2 [128n][256k]
    else if (idx < 163840)  { o = idx - 98304;  KS = 8; ph = u1h; pl = u1l; mtype = 2; }  // Uw1 [256n][256k]
    else if (idx < 196608)  { o = idx - 163840; KS = 8; ph = u2h; pl = u2l; mtype = 3; }  // Uw2 [128n][256k]
    else if (idx < 204800)  { o = idx - 196608; KS = 4; ph = g1h; pl = g1l; mtype = 4; }  // ft1 [64n][128k]
    else if (idx < 208896)  { o = idx - 204800; KS = 2; ph = g2h; pl = g2l; mtype = 5; }  // ft2 [64n][64k]
    else return;
    int t = o & 7;
    int l = (o >> 3) & 63;
    int frag = o >> 9;
    int ks = frag % KS;
    int nfr = frag / KS;
    int n = nfr * 16 + (l & 15);
    int k = ks * 32 + (l >> 4) * 8 + t;
    float v;
    switch (mtype) {
        case 0: v = mw1[k * 256 + n]; break;            // rows 0..255 of msg_w1 = [W1a;W1b]
        case 1: v = mw2[k * 128 + n]; break;
        case 2: v = uw1[k * 256 + n]; break;
        case 3: v = uw2[k * 128 + n]; break;
        case 4: v = f1w[k * 64 + n]; break;
        default: v = f2w[k * 64 + n]; break;
    }
    unsigned short hi, lo;
    split_bf(v, hi, lo);
    ph[o] = hi;
    pl[o] = lo;
}

// ============ megakernel: 1 block/graph, 8 waves, ~79KB LDS -> 2 blocks/CU ============
__global__ __launch_bounds__(512, 4) void k_mega(
    const float* __restrict__ nfeat, const float* __restrict__ efeat,
    const float* __restrict__ mfi,
    const float* __restrict__ enw, const float* __restrict__ enb,
    const float* __restrict__ uvg,
    const unsigned short* __restrict__ w1h, const unsigned short* __restrict__ w1l,
    const unsigned short* __restrict__ w2h, const unsigned short* __restrict__ w2l,
    const unsigned short* __restrict__ u1h, const unsigned short* __restrict__ u1l,
    const unsigned short* __restrict__ u2h, const unsigned short* __restrict__ u2l,
    const unsigned short* __restrict__ g1h, const unsigned short* __restrict__ g1l,
    const unsigned short* __restrict__ g2h, const unsigned short* __restrict__ g2l,
    const float* __restrict__ mb2, const float* __restrict__ ub1,
    const float* __restrict__ ub2, const float* __restrict__ f1b,
    const float* __restrict__ f2b,
    const int* __restrict__ fr, const int* __restrict__ to,
    float* __restrict__ out) {
    __shared__ __align__(16) unsigned int hSp[60][132];  // h packed hi|lo (31,680B)
    __shared__ __align__(16) char pool[42240];           // aggS 23,760 | zb 18,432
    __shared__ float uS[256], vS[256];
    __shared__ int cfS[144], ctRawS[144], ctCmpS[144];
    __shared__ float efS[144], msS[144];

    float* aggS = (float*)pool;            // [45][132]
    char* zb = pool + 23760;               // 9 frags x 2048B (hi 1024 | lo 1024)

    int g = blockIdx.x, tid = threadIdx.x;
    int wid = tid >> 6, lane = tid & 63;
    int l15 = lane & 15, l4 = lane >> 4, rloc = l4 * 4;

    if (tid < 256) uS[tid] = uvg[tid];
    else vS[tid - 256] = uvg[tid];
    if (tid < 144) {
        if (tid < EPG) {
            int fn = fr[g * EPG + tid] - g * NPG;
            int tn = to[g * EPG + tid] - g * NPG;
            cfS[tid] = fn;
            ctRawS[tid] = tn;
            ctCmpS[tid] = tn < 15 ? tn : tn - 15;
            efS[tid] = efeat[g * EPG + tid];
            msS[tid] = mfi[g * EPG + tid];
        } else {
            cfS[tid] = 0; ctRawS[tid] = 0; ctCmpS[tid] = 0; efS[tid] = 0.f; msS[tid] = 0.f;
        }
    }
    // encode h (packed split)
    for (int i = tid; i < 60 * 128; i += 512) {
        int r = i >> 7, d = i & 127;
        hSp[r][d] = pkv(nfeat[g * NPG + r] * enw[d] + enb[d]);
    }
    __syncthreads();

    float biasB = mb2[wid * 16 + l15];
    float biasD = ub2[wid * 16 + l15];

    for (int iter = 0; iter < NPROP; ++iter) {
        for (int i = tid; i < 45 * 132; i += 512) aggS[i] = 0.f;

        // ===== BB: edges. Zchunk[144][32] = G @ W1cat_c ; agg += Zchunk @ W2_c =====
        f32x4 accB[9] = {};
        for (int c = 0; c < 8; ++c) {
            __syncthreads();   // zb free (prev BB2 done); agg-zero fenced for epilogue
            // W2 frag for BB2 issued early, hidden under BB1
            U8 wbh, wbl;
            {
                int off = ((wid * 8 + c) * 64 + lane) * 8;
                wbh.u = *(const uint4*)(w2h + off);
                wbl.u = *(const uint4*)(w2l + off);
            }
            // BB1: wave w -> m-frag w (+8 for w==0), both n-frags of this chunk
            f32x4 az[2][2] = {};
#pragma unroll
            for (int kk = 0; kk < 8; ++kk) {
                int kloc = (kk & 3) * 32 + l4 * 8;
                bf16x8 ah0, al0, ah1, al1;
                {
                    int e = wid * 16 + l15;
                    int row = (kk < 4) ? cfS[e] : ctRawS[e];
                    unpack8(&hSp[row][kloc], ah0, al0);
                }
                if (wid == 0) {
                    int e = 128 + l15;
                    int row = (kk < 4) ? cfS[e] : ctRawS[e];
                    unpack8(&hSp[row][kloc], ah1, al1);
                }
#pragma unroll
                for (int nf = 0; nf < 2; ++nf) {
                    int off = (((c * 2 + nf) * 8 + kk) * 64 + lane) * 8;
                    U8 bh, bl;
                    bh.u = *(const uint4*)(w1h + off);
                    bl.u = *(const uint4*)(w1l + off);
                    MFMA3(ah0, al0, bh.v, bl.v, az[0][nf]);
                    if (wid == 0) { MFMA3(ah1, al1, bh.v, bl.v, az[1][nf]); }
                }
            }
            // epilogue: + edge affine, relu, split, write zb
#pragma unroll
            for (int mi = 0; mi < 2; ++mi) {
                if (mi == 1 && wid != 0) continue;
                int mf = (mi == 0) ? wid : 8;
#pragma unroll
                for (int nf = 0; nf < 2; ++nf) {
                    int kj = nf * 16 + l15;
                    int ncol = c * 32 + kj;
                    float uvn = uS[ncol], vvn = vS[ncol];
#pragma unroll
                    for (int r = 0; r < 4; ++r) {
                        int e = mf * 16 + rloc + r;
                        float val = fmaxf(az[mi][nf][r] + efS[e] * uvn + vvn, 0.f);
                        unsigned int p = pkv(val);
                        int base = mf * 2048 + (kj >> 3) * 256 + (rloc + r) * 16 + (kj & 7) * 2;
                        *(unsigned short*)(zb + base) = (unsigned short)(p >> 16);
                        *(unsigned short*)(zb + base + 1024) = (unsigned short)(p & 0xffffu);
                    }
                }
            }
            __syncthreads();
            // BB2: wave w -> output n-frag w, K = this chunk (32)
#pragma unroll
            for (int f = 0; f < 9; ++f) {
                bf16x8 zh = *(bf16x8*)(zb + f * 2048 + lane * 16);
                bf16x8 zl = *(bf16x8*)(zb + f * 2048 + 1024 + lane * 16);
                MFMA3(zh, zl, wbh.v, wbl.v, accB[f]);
            }
        }
        __syncthreads();
        // BB epilogue: mask + scatter into aggS
        {
            int col = wid * 16 + l15;
#pragma unroll
            for (int f = 0; f < 9; ++f)
#pragma unroll
                for (int r = 0; r < 4; ++r) {
                    int e = f * 16 + rloc + r;
                    if (e < EPG)
                        atomicAdd(&aggS[ctCmpS[e] * 132 + col], (accB[f][r] + biasB) * msS[e]);
                }
        }
        __syncthreads();

        // ===== CC: USchunk[64][32] = relu([agg|h] @ Uw1_c + b1) ; h += USchunk @ Uw2_c =====
        f32x4 accD[4] = {};
        int mfc = wid >> 1, nfc = wid & 1;
        int pC = mfc * 16 + l15;
        int arC = pC < 15 ? pC : (pC < 60 ? pC - 15 : 0);
        float mskC = ((pC >= 15 && pC < 30) || pC >= 60) ? 0.f : 1.f;
        int hrC = pC < 60 ? pC : 0;
        for (int c = 0; c < 8; ++c) {
            __syncthreads();   // zb free
            U8 wdh, wdl;
            {
                int off = ((wid * 8 + c) * 64 + lane) * 8;
                wdh.u = *(const uint4*)(u2h + off);
                wdl.u = *(const uint4*)(u2l + off);
            }
            f32x4 au = {};
#pragma unroll
            for (int kk = 0; kk < 8; ++kk) {
                bf16x8 ah, al;
                if (kk < 4) {
                    int k0 = kk * 32 + l4 * 8;
                    float4 z0 = *(const float4*)&aggS[arC * 132 + k0];
                    float4 z1 = *(const float4*)&aggS[arC * 132 + k0 + 4];
                    z0.x *= mskC; z0.y *= mskC; z0.z *= mskC; z0.w *= mskC;
                    z1.x *= mskC; z1.y *= mskC; z1.z *= mskC; z1.w *= mskC;
                    splitv(z0, z1, ah, al);
                } else {
                    int k0 = (kk - 4) * 32 + l4 * 8;
                    unpack8(&hSp[hrC][k0], ah, al);
                }
                int off = (((c * 2 + nfc) * 8 + kk) * 64 + lane) * 8;
                U8 bh, bl;
                bh.u = *(const uint4*)(u1h + off);
                bl.u = *(const uint4*)(u1l + off);
                MFMA3(ah, al, bh.v, bl.v, au);
            }
            // epilogue -> zb (frags 0..3)
            {
                int kj = nfc * 16 + l15;
                float b1v = ub1[c * 32 + kj];
#pragma unroll
                for (int r = 0; r < 4; ++r) {
                    float val = fmaxf(au[r] + b1v, 0.f);
                    unsigned int p = pkv(val);
                    int base = mfc * 2048 + (kj >> 3) * 256 + (rloc + r) * 16 + (kj & 7) * 2;
                    *(unsigned short*)(zb + base) = (unsigned short)(p >> 16);
                    *(unsigned short*)(zb + base + 1024) = (unsigned short)(p & 0xffffu);
                }
            }
            __syncthreads();
            // CC2: wave w -> output n-frag w
#pragma unroll
            for (int f = 0; f < 4; ++f) {
                bf16x8 zh = *(bf16x8*)(zb + f * 2048 + lane * 16);
                bf16x8 zl = *(bf16x8*)(zb + f * 2048 + 1024 + lane * 16);
                MFMA3(zh, zl, wdh.v, wdl.v, accD[f]);
            }
        }
        __syncthreads();
        // residual update (packed read-modify-write; cols disjoint per wave)
        {
            int col = wid * 16 + l15;
#pragma unroll
            for (int f = 0; f < 4; ++f)
#pragma unroll
                for (int r = 0; r < 4; ++r) {
                    int m = f * 16 + rloc + r;
                    if (m < 60) {
                        float v = upkv(hSp[m][col]) + accD[f][r] + biasD;
                        hSp[m][col] = pkv(v);
                    }
                }
        }
        __syncthreads();
    }

    // =================== tail: transform + Sinkhorn + score ===================
    float* hid = (float*)pool;             // [45][68] 12,240B
    float* tS = hid + 45 * 68;             // [45][68]
    float* la = tS + 45 * 68;              // [30][33]
    float* red = la + 30 * 33;             // [512]

    if (wid < 6) {  // ft1: hid = relu(rows @ f1w + b1)
        int mf = wid >> 1, nh = wid & 1;
        f32x4 acc[2] = {};
#pragma unroll
        for (int ks = 0; ks < 4; ++ks) {
            int k0 = ks * 32 + l4 * 8;
            int r = mf * 16 + l15;
            int hr = r < 15 ? r : (r < 45 ? r + 15 : 0);
            bf16x8 ah, al;
            unpack8(&hSp[hr][k0], ah, al);
#pragma unroll
            for (int j = 0; j < 2; ++j) {
                int nfr = nh * 2 + j;
                int off = ((nfr * 4 + ks) * 64 + lane) * 8;
                U8 th, tl;
                th.u = *(const uint4*)(g1h + off);
                tl.u = *(const uint4*)(g1l + off);
                MFMA3(ah, al, th.v, tl.v, acc[j]);
            }
        }
#pragma unroll
        for (int j = 0; j < 2; ++j) {
            int col = nh * 32 + j * 16 + l15;
            float bias = f1b[col];
#pragma unroll
            for (int r = 0; r < 4; ++r) {
                int m = mf * 16 + rloc + r;
                if (m < 45) hid[m * 68 + col] = fmaxf(acc[j][r] + bias, 0.f);
            }
        }
    }
    __syncthreads();
    if (wid < 6) {  // ft2: tS = hid @ f2w + b2
        int mf = wid >> 1, nh = wid & 1;
        f32x4 acc[2] = {};
#pragma unroll
        for (int ks = 0; ks < 2; ++ks) {
            int k0 = ks * 32 + l4 * 8;
            int r = mf * 16 + l15;
            int hr = r < 45 ? r : 0;
            float4 a0 = *(const float4*)&hid[hr * 68 + k0];
            float4 a1 = *(const float4*)&hid[hr * 68 + k0 + 4];
            bf16x8 ah, al;
            splitv(a0, a1, ah, al);
#pragma unroll
            for (int j = 0; j < 2; ++j) {
                int nfr = nh * 2 + j;
                int off = ((nfr * 2 + ks) * 64 + lane) * 8;
                U8 th, tl;
                th.u = *(const uint4*)(g2h + off);
                tl.u = *(const uint4*)(g2l + off);
                MFMA3(ah, al, th.v, tl.v, acc[j]);
            }
        }
#pragma unroll
        for (int j = 0; j < 2; ++j) {
            int col = nh * 32 + j * 16 + l15;
            float bias = f2b[col];
#pragma unroll
            for (int r = 0; r < 4; ++r) {
                int m = mf * 16 + rloc + r;
                if (m < 45) tS[m * 68 + col] = acc[j][r] + bias;
            }
        }
    }
    __syncthreads();
    for (int e = tid; e < NCC * NCC; e += 512) {
        int q = e / NCC, c = e % NCC;
        float s = 0.f;
        if (q < NQQ) {
#pragma unroll 4
            for (int k = 0; k < TT; k++) s += tS[q * 68 + k] * tS[(15 + c) * 68 + k];
            s *= 10.0f;
        }
        la[q * 33 + c] = s;
    }
    __syncthreads();
    int grp = tid >> 3, k8 = tid & 7;
    for (int it = 0; it < SKI; ++it) {
        if (grp < NCC) {
            float v0, v1, v2, v3, m;
            int c0 = k8 * 4;
            v0 = (c0 + 0 < NCC) ? la[grp * 33 + c0 + 0] : -INFINITY;
            v1 = (c0 + 1 < NCC) ? la[grp * 33 + c0 + 1] : -INFINITY;
            v2 = (c0 + 2 < NCC) ? la[grp * 33 + c0 + 2] : -INFINITY;
            v3 = (c0 + 3 < NCC) ? la[grp * 33 + c0 + 3] : -INFINITY;
            m = fmaxf(fmaxf(v0, v1), fmaxf(v2, v3));
            m = fmaxf(m, __shfl_xor(m, 1));
            m = fmaxf(m, __shfl_xor(m, 2));
            m = fmaxf(m, __shfl_xor(m, 4));
            float s = 0.f;
            if (c0 + 0 < NCC) s += __expf(v0 - m);
            if (c0 + 1 < NCC) s += __expf(v1 - m);
            if (c0 + 2 < NCC) s += __expf(v2 - m);
            if (c0 + 3 < NCC) s += __expf(v3 - m);
            s += __shfl_xor(s, 1);
            s += __shfl_xor(s, 2);
            s += __shfl_xor(s, 4);
            float lse = m + __logf(s);
            if (c0 + 0 < NCC) la[grp * 33 + c0 + 0] = v0 - lse;
            if (c0 + 1 < NCC) la[grp * 33 + c0 + 1] = v1 - lse;
            if (c0 + 2 < NCC) la[grp * 33 + c0 + 2] = v2 - lse;
            if (c0 + 3 < NCC) la[grp * 33 + c0 + 3] = v3 - lse;
        }
        __syncthreads();
        if (grp < NCC) {
            float v0, v1, v2, v3, m;
            int q0 = k8 * 4;
            v0 = (q0 + 0 < NCC) ? la[(q0 + 0) * 33 + grp] : -INFINITY;
            v1 = (q0 + 1 < NCC) ? la[(q0 + 1) * 33 + grp] : -INFINITY;
            v2 = (q0 + 2 < NCC) ? la[(q0 + 2) * 33 + grp] : -INFINITY;
            v3 = (q0 + 3 < NCC) ? la[(q0 + 3) * 33 + grp] : -INFINITY;
            m = fmaxf(fmaxf(v0, v1), fmaxf(v2, v3));
            m = fmaxf(m, __shfl_xor(m, 1));
            m = fmaxf(m, __shfl_xor(m, 2));
            m = fmaxf(m, __shfl_xor(m, 4));
            float s = 0.f;
            if (q0 + 0 < NCC) s += __expf(v0 - m);
            if (q0 + 1 < NCC) s += __expf(v1 - m);
            if (q0 + 2 < NCC) s += __expf(v2 - m);
            if (q0 + 3 < NCC) s += __expf(v3 - m);
            s += __shfl_xor(s, 1);
            s += __shfl_xor(s, 2);
            s += __shfl_xor(s, 4);
            float lse = m + __logf(s);
            if (q0 + 0 < NCC) la[(q0 + 0) * 33 + grp] = v0 - lse;
            if (q0 + 1 < NCC) la[(q0 + 1) * 33 + grp] = v1 - lse;
            if (q0 + 2 < NCC) la[(q0 + 2) * 33 + grp] = v2 - lse;
            if (q0 + 3 < NCC) la[(q0 + 3) * 33 + grp] = v3 - lse;
        }
        __syncthreads();
    }
    for (int e = tid; e < NCC * NCC; e += 512) {
        int q = e / NCC, c = e % NCC;
        la[q * 33 + c] = __expf(la[q * 33 + c]);
    }
    __syncthreads();
    float part = 0.f;
    for (int idx = tid; idx < NCC * D; idx += 512) {
        int q = idx >> 7, d = idx & 127;
        float mv = 0.f;
#pragma unroll 5
        for (int c = 0; c < NCC; c++) mv += la[q * 33 + c] * upkv(hSp[30 + c][d]);
        part += fmaxf(upkv(hSp[q][d]) - mv, 0.f);
    }
    red[tid] = part;
    __syncthreads();
    for (int s2 = 256; s2 > 0; s2 >>= 1) {
        if (tid < s2) red[tid] += red[tid + s2];
        __syncthreads();
    }
    if (tid == 0) out[g] = -red[0];
}

extern "C" void kernel_launch(void* const* d_in, const int* in_sizes, int n_in,
                              void* d_out, int out_size, void* d_ws, size_t ws_size,
                              hipStream_t stream) {
    const float* nf  = (const float*)d_in[0];
    const float* ef  = (const float*)d_in[1];
    const float* mfi = (const float*)d_in[2];
    const float* enw = (const float*)d_in[3];
    const float* enb = (const float*)d_in[4];
    const float* eew = (const float*)d_in[5];
    const float* eeb = (const float*)d_in[6];
    const float* mw1 = (const float*)d_in[7];
    const float* mb1 = (const float*)d_in[8];
    const float* mw2 = (const float*)d_in[9];
    const float* mb2 = (const float*)d_in[10];
    const float* uw1 = (const float*)d_in[11];
    const float* ub1 = (const float*)d_in[12];
    const float* uw2 = (const float*)d_in[13];
    const float* ub2 = (const float*)d_in[14];
    const float* f1w = (const float*)d_in[15];
    const float* f1b = (const float*)d_in[16];
    const float* f2w = (const float*)d_in[17];
    const float* f2b = (const float*)d_in[18];
    const int* fr = (const int*)d_in[19];
    const int* to = (const int*)d_in[20];
    float* out = (float*)d_out;

    char* base = (char*)d_ws;
    float* uv = (float*)base;
    unsigned short* w = (unsigned short*)(base + 4096);
    unsigned short* w1h = w;            unsigned short* w1l = w1h + 65536;
    unsigned short* w2h = w1l + 65536;  unsigned short* w2l = w2h + 32768;
    unsigned short* u1h = w2l + 32768;  unsigned short* u1l = u1h + 65536;
    unsigned short* u2h = u1l + 65536;  unsigned short* u2l = u2h + 32768;
    unsigned short* g1h = u2l + 32768;  unsigned short* g1l = g1h + 8192;
    unsigned short* g2h = g1l + 8192;   unsigned short* g2l = g2h + 4096;

    k_prep_uv<<<1, 256, 0, stream>>>(eew, eeb, mw1, mb1, uv);
    k_prep_w2<<<408, 512, 0, stream>>>(mw1, mw2, uw1, uw2, f1w, f2w,
                                       w1h, w1l, w2h, w2l, u1h, u1l, u2h, u2l,
                                       g1h, g1l, g2h, g2l);
    k_mega<<<BATCH, 512, 0, stream>>>(nf, ef, mfi, enw, enb, uv,
                                      w1h, w1l, w2h, w2l, u1h, u1l, u2h, u2l,
                                      g1h, g1l, g2h, g2l,
                                      mb2, ub1, ub2, f1b, f2b, fr, to, out);
}